// Round 1
// baseline (35.075 us; speedup 1.0000x reference)
//
#include <hip/hip_runtime.h>
#include <hip/hip_bf16.h>

// DecoderBlock: masked block-sparse linear (8x GEMM M=256,N=1024,K=1024)
// + BatchNorm1d (batch stats) + Swish.  bias cancels under BN -> skipped.

typedef short  short8  __attribute__((ext_vector_type(8)));
typedef float  f32x4   __attribute__((ext_vector_type(4)));
typedef unsigned short us4 __attribute__((ext_vector_type(4)));

static __device__ __forceinline__ unsigned short f2bf(float f) {
    unsigned int u = __float_as_uint(f);
    u += 0x7FFFu + ((u >> 16) & 1u);   // round-to-nearest-even (inputs finite)
    return (unsigned short)(u >> 16);
}

// ---------------- GEMM: y[b, g*1024 + n] = sum_k X[b, g*1024+k] * Wg[n,k] ----------------
// Block tile 128(M) x 128(N), BK=64, 4 waves each 64x64 (4x4 frags of 16x16x32 bf16 MFMA).
// grid = 128 * ksplit blocks; kh = upper bit selects K-half (partial sums to y0 / y1).
__global__ __launch_bounds__(256) void gemm_kernel(
    const float* __restrict__ x, const float* __restrict__ W,
    float* __restrict__ y0, float* __restrict__ y1, int ksplit)
{
    __shared__ __align__(16) char smem[32768];
    char* ldsA = smem;            // [128 rows][64 k] bf16, XOR-swizzled
    char* ldsB = smem + 16384;    // [128 rows][64 k] bf16, XOR-swizzled

    const int bid = blockIdx.x;
    const int kh  = bid >> 7;          // K-half (0 if grid==128)
    const int b7  = bid & 127;
    const int g   = b7 >> 4;           // channel block 0..7
    const int mt  = (b7 >> 3) & 1;     // M tile
    const int nt  = b7 & 7;            // N tile
    const int m0  = mt * 128;
    const int n0  = nt * 128;
    const int op  = n0 >> 8;           // o' within block (tile never crosses f=256 boundary)
    const int f0  = n0 & 255;
    const int o   = g * 4 + op;

    float* yp = kh ? y1 : y0;
    const int nsteps = 16 / ksplit;
    const int kbase  = kh * (nsteps * 64);

    const int t    = threadIdx.x;
    const int rsub = t >> 4;           // staging row sub-index 0..15
    const int c4   = t & 15;           // staging float4 column 0..15
    const int wave = t >> 6;
    const int lane = t & 63;
    const int wm   = wave >> 1, wn = wave & 1;
    const int lr   = lane & 15;        // frag row/col
    const int kq   = lane >> 4;        // k quarter 0..3

    f32x4 acc[4][4];
    const f32x4 zero = {0.f, 0.f, 0.f, 0.f};
#pragma unroll
    for (int i = 0; i < 4; ++i)
#pragma unroll
        for (int j = 0; j < 4; ++j) acc[i][j] = zero;

    const float* xbase = x + (size_t)m0 * 8192 + g * 1024;

    for (int st = 0; st < nsteps; ++st) {
        const int k0 = kbase + st * 64;
        const int cp = k0 >> 8;            // c' within block (BK=64 never crosses i=256)
        const int kc = k0 & 255;
        const float* wbase = W + ((size_t)((o * 32 + g * 4 + cp) * 256 + f0)) * 256 + kc;
        const float* xk = xbase + k0;

        __syncthreads();
#pragma unroll
        for (int p = 0; p < 8; ++p) {
            const int row = p * 16 + rsub;
            const float4 av = *(const float4*)(xk    + (size_t)row * 8192 + c4 * 4);
            const float4 bv = *(const float4*)(wbase + (size_t)row * 256  + c4 * 4);
            us4 ap, bp;
            ap[0] = f2bf(av.x); ap[1] = f2bf(av.y); ap[2] = f2bf(av.z); ap[3] = f2bf(av.w);
            bp[0] = f2bf(bv.x); bp[1] = f2bf(bv.y); bp[2] = f2bf(bv.z); bp[3] = f2bf(bv.w);
            const int bc = (c4 * 8) ^ ((row & 7) << 4);   // swizzled byte col
            *(us4*)(ldsA + row * 128 + bc) = ap;
            *(us4*)(ldsB + row * 128 + bc) = bp;
        }
        __syncthreads();

#pragma unroll
        for (int ks = 0; ks < 2; ++ks) {
            const int colb = ks * 64 + kq * 16;
            short8 af[4], bf[4];
#pragma unroll
            for (int i = 0; i < 4; ++i) {
                const int ra = wm * 64 + i * 16 + lr;
                af[i] = *(const short8*)(ldsA + ra * 128 + (colb ^ ((ra & 7) << 4)));
                const int rb = wn * 64 + i * 16 + lr;
                bf[i] = *(const short8*)(ldsB + rb * 128 + (colb ^ ((rb & 7) << 4)));
            }
#pragma unroll
            for (int i = 0; i < 4; ++i)
#pragma unroll
                for (int j = 0; j < 4; ++j)
                    acc[i][j] = __builtin_amdgcn_mfma_f32_16x16x32_bf16(af[i], bf[j], acc[i][j], 0, 0, 0);
        }
    }

    // epilogue: C/D layout col = lane&15, row = (lane>>4)*4 + reg  [m89/m91 verified]
#pragma unroll
    for (int i = 0; i < 4; ++i) {
        const int brow = m0 + wm * 64 + i * 16 + kq * 4;
#pragma unroll
        for (int j = 0; j < 4; ++j) {
            const int col = g * 1024 + n0 + wn * 64 + j * 16 + lr;
#pragma unroll
            for (int r = 0; r < 4; ++r)
                yp[(size_t)(brow + r) * 8192 + col] = acc[i][j][r];
        }
    }
}

// ---------------- BN (batch stats) + Swish ----------------
// 256 blocks x 32 features each; stage [256 rows][32 feats] in LDS, one global read.
__global__ __launch_bounds__(256) void bn_kernel(
    const float* __restrict__ y0, const float* __restrict__ y1,
    const float* __restrict__ gamma, const float* __restrict__ beta,
    float* __restrict__ out, int add2)
{
    __shared__ float tile[256][32];
    __shared__ float ps1[8][32];
    __shared__ float ps2[8][32];
    __shared__ float sa[32], sb[32];

    const int j0 = blockIdx.x * 32;
    const int t  = threadIdx.x;
    const int c8 = t & 7;     // float4 col (8 per 32 feats)
    const int rs = t >> 3;    // 0..31

#pragma unroll
    for (int p = 0; p < 8; ++p) {
        const int r = p * 32 + rs;
        float4 v = *(const float4*)(y0 + (size_t)r * 8192 + j0 + c8 * 4);
        if (add2) {
            const float4 w = *(const float4*)(y1 + (size_t)r * 8192 + j0 + c8 * 4);
            v.x += w.x; v.y += w.y; v.z += w.z; v.w += w.w;
        }
        *(float4*)&tile[r][c8 * 4] = v;
    }
    __syncthreads();

    // per-feature partial sums over 32-row chunks
    {
        const int j = t & 31, q = t >> 5;
        float s1 = 0.f, s2 = 0.f;
#pragma unroll
        for (int r = 0; r < 32; ++r) {
            const float v = tile[q * 32 + r][j];
            s1 += v; s2 += v * v;
        }
        ps1[q][j] = s1; ps2[q][j] = s2;
    }
    __syncthreads();
    if (t < 32) {
        float a1 = 0.f, a2 = 0.f;
#pragma unroll
        for (int q = 0; q < 8; ++q) { a1 += ps1[q][t]; a2 += ps2[q][t]; }
        const float mean = a1 * (1.0f / 256.0f);
        const float var  = a2 * (1.0f / 256.0f) - mean * mean;   // biased, matches jnp.var
        const float istd = rsqrtf(var + 1e-5f);
        const float gm = gamma[j0 + t], bt = beta[j0 + t];
        sa[t] = gm * istd;
        sb[t] = bt - mean * gm * istd;
    }
    __syncthreads();

#pragma unroll
    for (int p = 0; p < 8; ++p) {
        const int r = p * 32 + rs;
        const float4 v = *(const float4*)&tile[r][c8 * 4];
        float4 ov;
        {
            const float z = sa[c8 * 4 + 0] * v.x + sb[c8 * 4 + 0];
            ov.x = z / (1.0f + expf(-z));
        }
        {
            const float z = sa[c8 * 4 + 1] * v.y + sb[c8 * 4 + 1];
            ov.y = z / (1.0f + expf(-z));
        }
        {
            const float z = sa[c8 * 4 + 2] * v.z + sb[c8 * 4 + 2];
            ov.z = z / (1.0f + expf(-z));
        }
        {
            const float z = sa[c8 * 4 + 3] * v.w + sb[c8 * 4 + 3];
            ov.w = z / (1.0f + expf(-z));
        }
        *(float4*)(out + (size_t)r * 8192 + j0 + c8 * 4) = ov;
    }
}

extern "C" void kernel_launch(void* const* d_in, const int* in_sizes, int n_in,
                              void* d_out, int out_size, void* d_ws, size_t ws_size,
                              hipStream_t stream) {
    const float* x     = (const float*)d_in[0];
    const float* W     = (const float*)d_in[1];
    // d_in[2] = bias: mathematically cancelled by BN mean subtraction -> unused
    const float* gamma = (const float*)d_in[3];
    const float* beta  = (const float*)d_in[4];
    // d_in[5] = mask: implicit in block structure -> unused
    float* out = (float*)d_out;
    float* ws  = (float*)d_ws;

    const size_t need = (size_t)256 * 8192 * sizeof(float);   // 8 MB partial buffer
    const int split = (ws_size >= need) ? 2 : 1;

    gemm_kernel<<<128 * split, 256, 0, stream>>>(x, W, out, ws, split);
    bn_kernel<<<256, 256, 0, stream>>>(out, ws, gamma, beta, out, split == 2 ? 1 : 0);
}

// Round 2
// 32.398 us; speedup vs baseline: 1.0826x; 1.0826x over previous
//
#include <hip/hip_runtime.h>
#include <hip/hip_bf16.h>

// DecoderBlock: block-sparse masked linear (8 GEMMs M=256,N=1024,K=1024)
// + BatchNorm1d (batch stats; bias cancels) + Swish.
// GEMM: tile 256(M) x 64(N), BK=64, K split 4 ways -> grid 512 (2 blocks/CU).
// f32 tiles DMA'd to LDS via global_load_lds w/ pre-swizzled source (chunk ^= row&15);
// f32->bf16 conversion at fragment-read time; bf16 partial sums in d_ws.

typedef float f32x4  __attribute__((ext_vector_type(4)));
typedef short short8 __attribute__((ext_vector_type(8)));
typedef unsigned short u16x8 __attribute__((ext_vector_type(8)));

static __device__ __forceinline__ unsigned short f2bf(float f) {
    unsigned int u = __float_as_uint(f);
    u += 0x7FFFu + ((u >> 16) & 1u);          // RNE (inputs finite)
    return (unsigned short)(u >> 16);
}
static __device__ __forceinline__ float bf2f(unsigned short h) {
    return __uint_as_float((unsigned int)h << 16);
}
static __device__ __forceinline__ short8 pack8(f32x4 lo, f32x4 hi) {
    short8 v;
    v[0] = (short)f2bf(lo[0]); v[1] = (short)f2bf(lo[1]);
    v[2] = (short)f2bf(lo[2]); v[3] = (short)f2bf(lo[3]);
    v[4] = (short)f2bf(hi[0]); v[5] = (short)f2bf(hi[1]);
    v[6] = (short)f2bf(hi[2]); v[7] = (short)f2bf(hi[3]);
    return v;
}

#define GLL(gp, lp) __builtin_amdgcn_global_load_lds( \
    (const __attribute__((address_space(1))) unsigned int*)(gp), \
    (__attribute__((address_space(3))) unsigned int*)(lp), 16, 0, 0)

// ---------------- GEMM ----------------
// grid = 128*ksplit; block 256 thr (4 waves stacked in M, each 64x64 via 4x4 frags).
__global__ __launch_bounds__(256, 2) void gemm_kernel(
    const float* __restrict__ x, const float* __restrict__ W,
    unsigned short* __restrict__ pbf,   // bf16 partials (ksplit x 2M elems) or null
    float* __restrict__ pf32,           // f32 fallback output or null
    int ksplit)
{
    __shared__ __align__(16) char lds[81920];
    char* ldsA = lds;            // 256 rows x 64 f32 = 65536 B, chunk-swizzled
    char* ldsB = lds + 65536;    // 64 rows x 64 f32 = 16384 B

    // bijective XCD swizzle (nwg = 128*ksplit, always % 8 == 0)
    const int bid = ((int)blockIdx.x & 7) * (16 * ksplit) + ((int)blockIdx.x >> 3);
    const int kh  = bid >> 7;
    const int b7  = bid & 127;
    const int g   = b7 >> 4;           // channel block 0..7
    const int nt  = b7 & 15;           // 64-wide N tile
    const int o   = g * 4 + (nt >> 2);
    const int f0  = (nt & 3) * 64;
    const int nsteps = 16 / ksplit;

    const int t    = threadIdx.x;
    const int wave = t >> 6;
    const int lane = t & 63;
    const int lr   = lane & 15;
    const int kq   = lane >> 4;

    f32x4 acc[4][4];
    const f32x4 zero = {0.f, 0.f, 0.f, 0.f};
#pragma unroll
    for (int i = 0; i < 4; ++i)
#pragma unroll
        for (int j = 0; j < 4; ++j) acc[i][j] = zero;

    for (int st = 0; st < nsteps; ++st) {
        const int k0 = kh * (nsteps * 64) + st * 64;
        const int cp = k0 >> 8;            // c' within block (BK=64 stays inside i=256)
        const int kc = k0 & 255;
        const float* aSrc = x + g * 1024 + k0;                                   // row stride 8192
        const float* bSrc = W + ((size_t)((o * 32 + g * 4 + cp) * 256 + f0)) * 256 + kc; // row stride 256

        __syncthreads();                   // protect LDS reuse
        // stage A: 4096 16B-chunks, source chunk pre-swizzled (^ row&15)
#pragma unroll
        for (int i = 0; i < 16; ++i) {
            const int c = i * 256 + t, row = c >> 4, gc = (c & 15) ^ (row & 15);
            GLL(aSrc + (size_t)row * 8192 + gc * 4, ldsA + c * 16);
        }
        // stage B: 1024 chunks
#pragma unroll
        for (int i = 0; i < 4; ++i) {
            const int c = i * 256 + t, row = c >> 4, gc = (c & 15) ^ (row & 15);
            GLL(bSrc + (size_t)row * 256 + gc * 4, ldsB + c * 16);
        }
        __syncthreads();                   // drains vmcnt -> tiles ready

#pragma unroll
        for (int ks = 0; ks < 2; ++ks) {
            const int c0 = ks * 8 + kq * 2;    // 16B-chunk index of this lane's k-slice
            short8 af[4], bfr[4];
#pragma unroll
            for (int i = 0; i < 4; ++i) {
                const int ra = wave * 64 + i * 16 + lr, m = ra & 15;
                const f32x4 lo = *(const f32x4*)(ldsA + ra * 256 + ((c0 ^ m) * 16));
                const f32x4 hi = *(const f32x4*)(ldsA + ra * 256 + (((c0 + 1) ^ m) * 16));
                af[i] = pack8(lo, hi);
            }
#pragma unroll
            for (int j = 0; j < 4; ++j) {
                const int rb = j * 16 + lr, m = rb & 15;
                const f32x4 lo = *(const f32x4*)(ldsB + rb * 256 + ((c0 ^ m) * 16));
                const f32x4 hi = *(const f32x4*)(ldsB + rb * 256 + (((c0 + 1) ^ m) * 16));
                bfr[j] = pack8(lo, hi);
            }
#pragma unroll
            for (int i = 0; i < 4; ++i)
#pragma unroll
                for (int j = 0; j < 4; ++j)
                    acc[i][j] = __builtin_amdgcn_mfma_f32_16x16x32_bf16(af[i], bfr[j], acc[i][j], 0, 0, 0);
        }
    }

    // epilogue: C/D layout col = lane&15, row = (lane>>4)*4 + reg
    const int colbase = g * 1024 + nt * 64 + lr;
    if (pbf) {
        unsigned short* yp = pbf + (size_t)kh * 2097152;
#pragma unroll
        for (int i = 0; i < 4; ++i) {
            const int rbase = wave * 64 + i * 16 + kq * 4;
#pragma unroll
            for (int j = 0; j < 4; ++j)
#pragma unroll
                for (int r = 0; r < 4; ++r)
                    yp[(size_t)(rbase + r) * 8192 + colbase + j * 16] = f2bf(acc[i][j][r]);
        }
    } else {
#pragma unroll
        for (int i = 0; i < 4; ++i) {
            const int rbase = wave * 64 + i * 16 + kq * 4;
#pragma unroll
            for (int j = 0; j < 4; ++j)
#pragma unroll
                for (int r = 0; r < 4; ++r)
                    pf32[(size_t)(rbase + r) * 8192 + colbase + j * 16] = acc[i][j][r];
        }
    }
}

// ---------------- BN (batch stats) + Swish ----------------
// 256 blocks x 32 features; sum ksplit bf16 partials, stats over 256 rows, swish.
__global__ __launch_bounds__(256) void bn_kernel(
    const unsigned short* __restrict__ P, const float* __restrict__ fy,
    const float* __restrict__ gamma, const float* __restrict__ beta,
    float* __restrict__ out, int ksplit)
{
    __shared__ float tile[256][32];
    __shared__ float ps1[8][32];
    __shared__ float ps2[8][32];
    __shared__ float sa[32], sb[32];

    const int j0 = blockIdx.x * 32;
    const int t  = threadIdx.x;

    // load & sum partials: 8 feats (short8) per thread, 64 rows per pass
    {
        const int c4 = t & 3, rs = t >> 2;
#pragma unroll
        for (int p = 0; p < 4; ++p) {
            const int r = p * 64 + rs;
            float a0 = 0.f, a1 = 0.f, a2 = 0.f, a3 = 0.f, a4 = 0.f, a5 = 0.f, a6 = 0.f, a7 = 0.f;
            if (P) {
                for (int kb = 0; kb < ksplit; ++kb) {
                    const u16x8 v = *(const u16x8*)(P + (size_t)kb * 2097152 + (size_t)r * 8192 + j0 + c4 * 8);
                    a0 += bf2f(v[0]); a1 += bf2f(v[1]); a2 += bf2f(v[2]); a3 += bf2f(v[3]);
                    a4 += bf2f(v[4]); a5 += bf2f(v[5]); a6 += bf2f(v[6]); a7 += bf2f(v[7]);
                }
            } else {
                const f32x4 v0 = *(const f32x4*)(fy + (size_t)r * 8192 + j0 + c4 * 8);
                const f32x4 v1 = *(const f32x4*)(fy + (size_t)r * 8192 + j0 + c4 * 8 + 4);
                a0 = v0[0]; a1 = v0[1]; a2 = v0[2]; a3 = v0[3];
                a4 = v1[0]; a5 = v1[1]; a6 = v1[2]; a7 = v1[3];
            }
            float* tp = &tile[r][c4 * 8];
            tp[0] = a0; tp[1] = a1; tp[2] = a2; tp[3] = a3;
            tp[4] = a4; tp[5] = a5; tp[6] = a6; tp[7] = a7;
        }
    }
    __syncthreads();

    {   // per-feature partial sums over 32-row chunks
        const int j = t & 31, q = t >> 5;
        float s1 = 0.f, s2 = 0.f;
#pragma unroll
        for (int rr = 0; rr < 32; ++rr) {
            const float v = tile[q * 32 + rr][j];
            s1 += v; s2 += v * v;
        }
        ps1[q][j] = s1; ps2[q][j] = s2;
    }
    __syncthreads();
    if (t < 32) {
        float a1 = 0.f, a2 = 0.f;
#pragma unroll
        for (int q = 0; q < 8; ++q) { a1 += ps1[q][t]; a2 += ps2[q][t]; }
        const float mean = a1 * (1.0f / 256.0f);
        const float var  = a2 * (1.0f / 256.0f) - mean * mean;  // biased, matches jnp.var
        const float istd = rsqrtf(var + 1e-5f);
        const float gm = gamma[j0 + t], bt = beta[j0 + t];
        sa[t] = gm * istd;
        sb[t] = bt - mean * gm * istd;
    }
    __syncthreads();

    {   // normalize + swish + store
        const int c8 = t & 7, rs = t >> 3;
#pragma unroll
        for (int p = 0; p < 8; ++p) {
            const int r = p * 32 + rs;
            const float4 v = *(const float4*)&tile[r][c8 * 4];
            float4 ov;
            { const float z = sa[c8 * 4 + 0] * v.x + sb[c8 * 4 + 0]; ov.x = z / (1.0f + expf(-z)); }
            { const float z = sa[c8 * 4 + 1] * v.y + sb[c8 * 4 + 1]; ov.y = z / (1.0f + expf(-z)); }
            { const float z = sa[c8 * 4 + 2] * v.z + sb[c8 * 4 + 2]; ov.z = z / (1.0f + expf(-z)); }
            { const float z = sa[c8 * 4 + 3] * v.w + sb[c8 * 4 + 3]; ov.w = z / (1.0f + expf(-z)); }
            *(float4*)(out + (size_t)r * 8192 + j0 + c8 * 4) = ov;
        }
    }
}

extern "C" void kernel_launch(void* const* d_in, const int* in_sizes, int n_in,
                              void* d_out, int out_size, void* d_ws, size_t ws_size,
                              hipStream_t stream) {
    const float* x     = (const float*)d_in[0];
    const float* W     = (const float*)d_in[1];
    // d_in[2] = bias: cancelled exactly by BN mean subtraction -> unused
    const float* gamma = (const float*)d_in[3];
    const float* beta  = (const float*)d_in[4];
    // d_in[5] = mask: implicit in block structure -> unused
    float* out = (float*)d_out;

    const size_t MBUF = 2097152ull * sizeof(unsigned short);  // 4 MB per bf16 partial
    int ksplit;
    unsigned short* pbf = nullptr;
    float* pf32 = nullptr;
    if      (ws_size >= 4 * MBUF) { ksplit = 4; pbf = (unsigned short*)d_ws; }
    else if (ws_size >= 2 * MBUF) { ksplit = 2; pbf = (unsigned short*)d_ws; }
    else if (ws_size >= 1 * MBUF) { ksplit = 1; pbf = (unsigned short*)d_ws; }
    else                          { ksplit = 1; pf32 = out; }                 // f32 in-place fallback

    gemm_kernel<<<128 * ksplit, 256, 0, stream>>>(x, W, pbf, pf32, ksplit);
    bn_kernel<<<256, 256, 0, stream>>>(pbf, out, gamma, beta, out, ksplit);
}